// Round 6
// baseline (312.985 us; speedup 1.0000x reference)
//
#include <hip/hip_runtime.h>

typedef unsigned short ushort_t;
typedef __bf16 bf16_t;
typedef float floatx4 __attribute__((ext_vector_type(4)));
typedef bf16_t bf16x8 __attribute__((ext_vector_type(8)));
typedef float f32x4 __attribute__((ext_vector_type(4)));
typedef unsigned short u16x4 __attribute__((ext_vector_type(4)));
typedef unsigned short u16x8 __attribute__((ext_vector_type(8)));
typedef unsigned int u32x2 __attribute__((ext_vector_type(2)));

#define NTOK 4096
#define NHEAD 12
#define HD 64
#define DMODEL 768
#define NROWS 8192  // 2*4096
#define NBH 24

__device__ __forceinline__ ushort_t f2bf(float f) {
  union { float f; unsigned u; } v; v.f = f;
  unsigned u = v.u;
  unsigned r = u + 0x7fffu + ((u >> 16) & 1u);
  return (ushort_t)(r >> 16);
}

__device__ __forceinline__ float bf2f(ushort_t s) {
  union { unsigned u; float f; } v; v.u = (unsigned)s << 16; return v.f;
}

__device__ __forceinline__ void async16(const void* g, void* l) {
  __builtin_amdgcn_global_load_lds(
      (const __attribute__((address_space(1))) void*)g,
      (__attribute__((address_space(3))) void*)l, 16, 0, 0);
}

// ---------------- converters ----------------

__global__ __launch_bounds__(256) void transpose_w4(
    const float* __restrict__ s0, const float* __restrict__ s1,
    const float* __restrict__ s2, const float* __restrict__ s3,
    ushort_t* __restrict__ d_qkv, ushort_t* __restrict__ d_o) {
  __shared__ float t[32][33];
  const int m = blockIdx.z;
  const float* src = (m == 0) ? s0 : (m == 1) ? s1 : (m == 2) ? s2 : s3;
  ushort_t* dst = (m < 3) ? (d_qkv + (size_t)m * DMODEL * DMODEL) : d_o;
  const int bi = blockIdx.x, bj = blockIdx.y;
  const int r = threadIdx.x >> 5, c = threadIdx.x & 31;
  for (int p = 0; p < 4; ++p)
    t[r + p * 8][c] = src[(size_t)(bi * 32 + r + p * 8) * DMODEL + bj * 32 + c];
  __syncthreads();
  for (int p = 0; p < 4; ++p)
    dst[(size_t)(bj * 32 + r + p * 8) * DMODEL + bi * 32 + c] = f2bf(t[c][r + p * 8]);
}

__global__ void convert_x(const float* __restrict__ in, ushort_t* __restrict__ out) {
  int idx = blockIdx.x * 256 + threadIdx.x;
  f32x4 v = ((const f32x4*)in)[idx];
  u16x4 o;
  o.x = f2bf(v.x); o.y = f2bf(v.y); o.z = f2bf(v.z); o.w = f2bf(v.w);
  ((u16x4*)out)[idx] = o;
}

// ---------------- GEMM: C[M x N] = A[M x K] * B^T (B stored [N][K]) ----------------
// mode 0: QKV epilogue (Q scaled (1/8)*log2e; V -> transposed [bh][d][n] via shfl-pair).
// mode 2: out-proj with FUSED split-combine A-staging (A = (o0+o1)/(l0+l1)), bias, fp32 out.
__global__ __launch_bounds__(256) void gemm_bt(
    const ushort_t* __restrict__ A, const ushort_t* __restrict__ B, int K, int mode,
    ushort_t* __restrict__ q_ws, ushort_t* __restrict__ k_ws, ushort_t* __restrict__ v_ws,
    float* __restrict__ outF, const float* __restrict__ bias,
    const ushort_t* __restrict__ opart, const float* __restrict__ lpart) {
  __shared__ __align__(16) ushort_t a_lds[128 * 32];
  __shared__ __align__(16) ushort_t b_lds[128 * 32];
  const int tid = threadIdx.x;
  const int w = tid >> 6, lane = tid & 63;
  const int quad = lane >> 4, l16 = lane & 15;
  const int wm = w >> 1, wn = w & 1;
  const size_t row0 = (size_t)blockIdx.x * 128;
  const size_t col0 = (size_t)blockIdx.y * 128;

  const int srow = w * 32 + (lane >> 2);
  const int kbyte = (lane & 3) * 16;
  const char* aG = (const char*)(A + (row0 + srow) * (size_t)K) + kbyte;
  const char* bG = (const char*)(B + (col0 + srow) * (size_t)K) + kbyte;
  const size_t rstep = (size_t)16 * K * 2;
  char* aL = (char*)a_lds + (size_t)(w * 2) * 1024;
  char* bL = (char*)b_lds + (size_t)(w * 2) * 1024;

  floatx4 acc[4][4];
  for (int i = 0; i < 4; ++i)
    for (int j = 0; j < 4; ++j) acc[i][j] = (floatx4){0.f, 0.f, 0.f, 0.f};

  const int nk = K / 32;
  for (int kt = 0; kt < nk; ++kt) {
    const size_t koff = (size_t)kt * 64;
    __syncthreads();
    if (mode == 2) {
      // fused combine: stage A = (o0+o1)/(l0+l1) as bf16 into the A slots
      const int col = kt * 32 + (lane & 3) * 8;  // d_model col of this lane's 8 elems
      const int h = col >> 6, dd = col & 63;
#pragma unroll
      for (int sl = 0; sl < 2; ++sl) {
        int row = (int)row0 + srow + sl * 16;
        int b = row >> 12, n = row & 4095;
        int bh = b * NHEAD + h;
        size_t i0 = ((size_t)bh * NTOK + n) * HD + dd;
        size_t i1 = i0 + (size_t)NBH * NTOK * HD;
        u16x8 a = *(const u16x8*)&opart[i0];
        u16x8 c = *(const u16x8*)&opart[i1];
        float inv = 1.0f / (lpart[(size_t)bh * NTOK + n] + lpart[(size_t)(NBH + bh) * NTOK + n]);
        u16x8 o;
#pragma unroll
        for (int j = 0; j < 8; ++j) o[j] = f2bf((bf2f(a[j]) + bf2f(c[j])) * inv);
        *(u16x8*)(aL + sl * 1024 + (size_t)lane * 16) = o;
      }
    } else {
      async16(aG + koff, aL);
      async16(aG + koff + rstep, aL + 1024);
    }
    async16(bG + koff, bL);
    async16(bG + koff + rstep, bL + 1024);
    __syncthreads();
    bf16x8 af[4], bfr[4];
    for (int mt = 0; mt < 4; ++mt)
      af[mt] = *(bf16x8*)&a_lds[(wm * 64 + mt * 16 + l16) * 32 + quad * 8];
    for (int nt = 0; nt < 4; ++nt)
      bfr[nt] = *(bf16x8*)&b_lds[(wn * 64 + nt * 16 + l16) * 32 + quad * 8];
    for (int mt = 0; mt < 4; ++mt)
      for (int nt = 0; nt < 4; ++nt)
        acc[mt][nt] = __builtin_amdgcn_mfma_f32_16x16x32_bf16(af[mt], bfr[nt], acc[mt][nt], 0, 0, 0);
  }

  if (mode == 0) {
    const int which = (int)(col0 / DMODEL);
    if (which < 2) {
      ushort_t* dstT = (which == 0) ? q_ws : k_ws;
      const float scale = (which == 0) ? 0.125f * 1.4426950408889634f : 1.0f;
      for (int mt = 0; mt < 4; ++mt) {
        int gr = (int)row0 + wm * 64 + mt * 16 + quad * 4;
        int b = gr >> 12;
        int n0 = gr & 4095;
        for (int nt = 0; nt < 4; ++nt) {
          int gc = (int)col0 + wn * 64 + nt * 16 + l16;
          int cc = gc - which * DMODEL;
          int h = cc >> 6, d = cc & 63;
          size_t base = ((size_t)(b * NHEAD + h) * NTOK + n0) * HD + d;
          for (int r = 0; r < 4; ++r)
            dstT[base + (size_t)r * HD] = f2bf(acc[mt][nt][r] * scale);
        }
      }
    } else {  // V: transposed [bh][d][token]; pair quads via shfl -> 16B stores
      for (int mt = 0; mt < 4; ++mt) {
        int gr = (int)row0 + wm * 64 + mt * 16 + quad * 4;
        int b = gr >> 12;
        int n0 = gr & 4095;  // token of r=0 (includes quad*4)
        for (int nt = 0; nt < 4; ++nt) {
          int gc = (int)col0 + wn * 64 + nt * 16 + l16;
          int cc = gc - 2 * DMODEL;
          int h = cc >> 6, d = cc & 63;
          u16x4 ov;
          for (int r = 0; r < 4; ++r) ov[r] = f2bf(acc[mt][nt][r]);
          unsigned d0 = ((unsigned*)&ov)[0], d1 = ((unsigned*)&ov)[1];
          unsigned p0 = (unsigned)__shfl_xor((int)d0, 16);
          unsigned p1 = (unsigned)__shfl_xor((int)d1, 16);
          if (!(quad & 1)) {  // even quads store their 4 toks + partner's 4
            u16x8 pk;
            ((unsigned*)&pk)[0] = d0; ((unsigned*)&pk)[1] = d1;
            ((unsigned*)&pk)[2] = p0; ((unsigned*)&pk)[3] = p1;
            *(u16x8*)&v_ws[((size_t)(b * NHEAD + h) * HD + d) * NTOK + n0] = pk;
          }
        }
      }
    }
  } else {  // mode 2 epilogue: bias + fp32 store
    for (int mt = 0; mt < 4; ++mt) {
      int gr = (int)row0 + wm * 64 + mt * 16 + quad * 4;
      for (int nt = 0; nt < 4; ++nt) {
        int gc = (int)col0 + wn * 64 + nt * 16 + l16;
        float bv = bias[gc];
        for (int r = 0; r < 4; ++r)
          outF[(size_t)(gr + r) * DMODEL + gc] = acc[mt][nt][r] + bv;
      }
    }
  }
}

// ---------------- flash attention v6: 2 waves x 64 q-rows, BQ=128, split x2 ----------------
// Same math as v5 (fixed-max-free softmax, S^T, fragment-linear LDS, dbuf K/V,
// pairing, XCD homing). Waves widened to 64q (qf=4): LDS B/score 14.6 -> 8,
// half the barriers per score, 2x VALU/MFMA per barrier.
__global__ __launch_bounds__(128, 2) void attn6(
    const ushort_t* __restrict__ Qh, const ushort_t* __restrict__ Kh,
    const ushort_t* __restrict__ Vt, ushort_t* __restrict__ o_part,
    float* __restrict__ l_part) {
  __shared__ __align__(16) ushort_t k_lds[2][8 * 512];   // A-frag linear, dbuf (16 KB)
  __shared__ __align__(16) ushort_t v_lds[2][8 * 512];   // B-frag linear V^T, dbuf (16 KB)
  __shared__ __align__(16) ushort_t q_lds[16 * 512];     // Q stage / P region (16 KB)
  const int tid = threadIdx.x;
  const int w = tid >> 6, lane = tid & 63;
  const int quad = lane >> 4, l16 = lane & 15;
  const int bh = blockIdx.x;   // XCD = bh % 8
  const int split = blockIdx.z;
  const size_t hbase = (size_t)bh * NTOK * HD;
  const ushort_t* Qb = Qh + hbase;
  const ushort_t* Kb = Kh + hbase;
  const ushort_t* Vb = Vt + hbase;  // [64][4096]
  const size_t obase = ((size_t)split * NBH + bh) * NTOK * HD;
  const size_t lbase = ((size_t)split * NBH + bh) * NTOK;

  for (int phase = 0; phase < 2; ++phase) {
    const int qt = (phase == 0) ? (int)blockIdx.y : 31 - (int)blockIdx.y;
    const int Q0 = qt * 128;
    const int nkt = 2 * qt + 2;
    const int kt_lo = (split == 0) ? 0 : nkt / 2;
    const int kt_hi = (split == 0) ? nkt / 2 : nkt;
    const int nit = kt_hi - kt_lo;  // == qt+1, uniform over pairing
    __syncthreads();  // protect q/p + k/v regions across phases
    // stage Q: 8 slots per wave (slot s=w*8+i: qf=i>>1, d-half=i&1)
#pragma unroll
    for (int i = 0; i < 8; ++i) {
      int s = w * 8 + i;
      async16(Qb + (size_t)(Q0 + w * 64 + (i >> 1) * 16 + l16) * HD + (i & 1) * 32 + quad * 8,
              (char*)q_lds + s * 1024);
    }
    // prefetch first K/V tile into buf0 (per wave 4+4 slots)
    {
      const int k0p = kt_lo * 64;
#pragma unroll
      for (int i = 0; i < 4; ++i) {
        int s = w * 4 + i;
        async16(Kb + (size_t)(k0p + (s >> 1) * 16 + l16) * HD + (s & 1) * 32 + quad * 8,
                (char*)k_lds + s * 1024);
        async16(Vb + (size_t)((s >> 1) * 16 + l16) * NTOK + k0p + (s & 1) * 32 + quad * 8,
                (char*)v_lds + s * 1024);
      }
    }
    __asm volatile("s_waitcnt vmcnt(0)" ::: "memory");
    bf16x8 qr[4][2];  // own wave's Q slots, loop-invariant
#pragma unroll
    for (int qf = 0; qf < 4; ++qf)
#pragma unroll
      for (int hh = 0; hh < 2; ++hh)
        qr[qf][hh] = *(const bf16x8*)((const char*)q_lds + ((w * 8 + qf * 2 + hh) * 1024) + lane * 16);

    floatx4 o[4][4];
    float lp[4] = {0.f, 0.f, 0.f, 0.f};
#pragma unroll
    for (int qf = 0; qf < 4; ++qf)
#pragma unroll
      for (int dt = 0; dt < 4; ++dt) o[qf][dt] = (floatx4){0.f, 0.f, 0.f, 0.f};

    const int wq0 = Q0 + w * 64;

    for (int it = 0; it < nit; ++it) {
      const int kt = kt_lo + it;
      const int cur = it & 1;
      __syncthreads();  // buf[cur] staged (vmcnt drained) + buf[cur^1] free
      if (it + 1 < nit) {
        const int k1 = (kt + 1) * 64;
#pragma unroll
        for (int i = 0; i < 4; ++i) {
          int s = w * 4 + i;
          async16(Kb + (size_t)(k1 + (s >> 1) * 16 + l16) * HD + (s & 1) * 32 + quad * 8,
                  (char*)k_lds + (cur ^ 1) * 8192 + s * 1024);
          async16(Vb + (size_t)((s >> 1) * 16 + l16) * NTOK + k1 + (s & 1) * 32 + quad * 8,
                  (char*)v_lds + (cur ^ 1) * 8192 + s * 1024);
        }
      }
      const int k0 = kt * 64;
      if (k0 > wq0 + 63) continue;  // tile fully above this wave's diagonal
      const char* kb = (const char*)k_lds + cur * 8192;
      const char* vb = (const char*)v_lds + cur * 8192;
      const bool need_mask = (k0 + 63 > wq0);

      // process key sub-tiles in mt-pairs (caps st register liveness at 32)
#pragma unroll
      for (int half = 0; half < 2; ++half) {
        floatx4 st[4][2];
#pragma unroll
        for (int m2 = 0; m2 < 2; ++m2) {
          const int mt = half * 2 + m2;
          bf16x8 kf0 = *(const bf16x8*)(kb + (mt * 2 + 0) * 1024 + lane * 16);
          bf16x8 kf1 = *(const bf16x8*)(kb + (mt * 2 + 1) * 1024 + lane * 16);
#pragma unroll
          for (int qf = 0; qf < 4; ++qf) {
            floatx4 z = (floatx4){0.f, 0.f, 0.f, 0.f};
            z = __builtin_amdgcn_mfma_f32_16x16x32_bf16(kf0, qr[qf][0], z, 0, 0, 0);
            z = __builtin_amdgcn_mfma_f32_16x16x32_bf16(kf1, qr[qf][1], z, 0, 0, 0);
            st[qf][m2] = z;
          }
        }
#pragma unroll
        for (int qf = 0; qf < 4; ++qf) {
          const int qg = wq0 + qf * 16 + l16;
          float sum = 0.f;
#pragma unroll
          for (int m2 = 0; m2 < 2; ++m2) {
            const int mt = half * 2 + m2;
            float p[4];
#pragma unroll
            for (int r = 0; r < 4; ++r) {
              float e = __builtin_exp2f(st[qf][m2][r]);  // Q pre-scaled by log2e/8
              if (need_mask && (k0 + mt * 16 + quad * 4 + r > qg)) e = 0.f;
              p[r] = e;
              sum += e;
            }
            union { float f; unsigned u; } c0, c1, c2, c3;
            c0.f = p[0]; c1.f = p[1]; c2.f = p[2]; c3.f = p[3];
            u32x2 pk;
            pk.x = __builtin_amdgcn_perm(c1.u, c0.u, 0x07060302u);
            pk.y = __builtin_amdgcn_perm(c3.u, c2.u, 0x07060302u);
            char* dst = (char*)q_lds + ((w * 8 + qf * 2 + (mt >> 1)) * 1024)
                        + ((((mt & 1) * 2 + (quad >> 1)) * 16 + l16) * 16) + (quad & 1) * 8;
            *(u32x2*)dst = pk;
          }
          lp[qf] += sum;
        }
      }
      __asm volatile("s_waitcnt lgkmcnt(0)" ::: "memory");
      bf16x8 pf[4][2];
#pragma unroll
      for (int qf = 0; qf < 4; ++qf)
#pragma unroll
        for (int hh = 0; hh < 2; ++hh)
          pf[qf][hh] = *(const bf16x8*)((const char*)q_lds + ((w * 8 + qf * 2 + hh) * 1024) + lane * 16);
#pragma unroll
      for (int dt = 0; dt < 4; ++dt) {
        bf16x8 vf0 = *(const bf16x8*)(vb + (dt * 2 + 0) * 1024 + lane * 16);
        bf16x8 vf1 = *(const bf16x8*)(vb + (dt * 2 + 1) * 1024 + lane * 16);
#pragma unroll
        for (int qf = 0; qf < 4; ++qf) {
          o[qf][dt] = __builtin_amdgcn_mfma_f32_16x16x32_bf16(pf[qf][0], vf0, o[qf][dt], 0, 0, 0);
          o[qf][dt] = __builtin_amdgcn_mfma_f32_16x16x32_bf16(pf[qf][1], vf1, o[qf][dt], 0, 0, 0);
        }
      }
    }

    // epilogue: write unnormalized partial o (bf16) + per-row l (fp32)
#pragma unroll
    for (int qf = 0; qf < 4; ++qf) {
      float lf = lp[qf];
      lf += __shfl_xor(lf, 16);
      lf += __shfl_xor(lf, 32);
#pragma unroll
      for (int r = 0; r < 4; ++r) {
        float lq = __shfl(lf, quad * 4 + r);
        int qg = wq0 + qf * 16 + quad * 4 + r;
        size_t base = obase + (size_t)qg * HD;
#pragma unroll
        for (int dt = 0; dt < 4; ++dt)
          o_part[base + dt * 16 + l16] = f2bf(o[qf][dt][r]);
        if (l16 == 0) l_part[lbase + qg] = lq;
      }
    }
  }
}

// ---------------- launch ----------------
extern "C" void kernel_launch(void* const* d_in, const int* in_sizes, int n_in,
                              void* d_out, int out_size, void* d_ws, size_t ws_size,
                              hipStream_t stream) {
  const float* x  = (const float*)d_in[0];
  const float* wq = (const float*)d_in[1];
  const float* wk = (const float*)d_in[2];
  const float* wv = (const float*)d_in[3];
  const float* wo = (const float*)d_in[4];
  const float* bo = (const float*)d_in[5];
  float* out = (float*)d_out;

  ushort_t* ws = (ushort_t*)d_ws;
  ushort_t* wqkvT = ws;                               // 2304*768
  ushort_t* woutT = wqkvT + 2304 * 768;               // 768*768
  ushort_t* xbf   = woutT + 768 * 768;                // 8192*768 (x bf16)
  ushort_t* qh    = xbf + (size_t)NROWS * DMODEL;     // 24*4096*64
  ushort_t* kh    = qh + (size_t)NBH * NTOK * HD;
  ushort_t* vt    = kh + (size_t)NBH * NTOK * HD;     // V transposed [bh][64][4096]
  ushort_t* opart = vt + (size_t)NBH * NTOK * HD;     // 2*24*4096*64 bf16
  float*    lpart = (float*)(opart + (size_t)2 * NBH * NTOK * HD);  // 2*24*4096 fp32

  transpose_w4<<<dim3(24, 24, 4), 256, 0, stream>>>(wq, wk, wv, wo, wqkvT, woutT);
  convert_x<<<6144, 256, 0, stream>>>(x, xbf);

  gemm_bt<<<dim3(64, 18), 256, 0, stream>>>(xbf, wqkvT, DMODEL, 0,
                                            qh, kh, vt, nullptr, nullptr, nullptr, nullptr);
  attn6<<<dim3(24, 16, 2), 128, 0, stream>>>(qh, kh, vt, opart, lpart);
  gemm_bt<<<dim3(64, 6), 256, 0, stream>>>(opart, woutT, DMODEL, 2,
                                           nullptr, nullptr, nullptr, out, bo, opart, lpart);
}

// Round 8
// 282.805 us; speedup vs baseline: 1.1067x; 1.1067x over previous
//
#include <hip/hip_runtime.h>

typedef unsigned short ushort_t;
typedef __bf16 bf16_t;
typedef float floatx4 __attribute__((ext_vector_type(4)));
typedef bf16_t bf16x8 __attribute__((ext_vector_type(8)));
typedef bf16_t bf16x4 __attribute__((ext_vector_type(4)));
typedef short s16x4 __attribute__((ext_vector_type(4)));
typedef float f32x4 __attribute__((ext_vector_type(4)));
typedef unsigned short u16x4 __attribute__((ext_vector_type(4)));
typedef unsigned short u16x8 __attribute__((ext_vector_type(8)));
typedef unsigned int u32x2 __attribute__((ext_vector_type(2)));

#define NTOK 4096
#define NHEAD 12
#define HD 64
#define DMODEL 768
#define NROWS 8192  // 2*4096
#define NBH 24

__device__ __forceinline__ ushort_t f2bf(float f) {
  union { float f; unsigned u; } v; v.f = f;
  unsigned u = v.u;
  unsigned r = u + 0x7fffu + ((u >> 16) & 1u);
  return (ushort_t)(r >> 16);
}

__device__ __forceinline__ float bf2f(ushort_t s) {
  union { unsigned u; float f; } v; v.u = (unsigned)s << 16; return v.f;
}

__device__ __forceinline__ void async16(const void* g, void* l) {
  __builtin_amdgcn_global_load_lds(
      (const __attribute__((address_space(1))) void*)g,
      (__attribute__((address_space(3))) void*)l, 16, 0, 0);
}

// K=16 bf16 MFMA: A/B = 4 bf16 (2 VGPRs). Builtin name differs across clang
// versions; host pass defines neither -> guard with __HIP_DEVICE_COMPILE__.
__device__ __forceinline__ floatx4 mfma16(unsigned a0, unsigned a1,
                                          unsigned b0, unsigned b1, floatx4 c) {
#if defined(__HIP_DEVICE_COMPILE__)
#if __has_builtin(__builtin_amdgcn_mfma_f32_16x16x16_bf16)
  union { unsigned u[2]; bf16x4 v; } A, B;
  A.u[0] = a0; A.u[1] = a1; B.u[0] = b0; B.u[1] = b1;
  return __builtin_amdgcn_mfma_f32_16x16x16_bf16(A.v, B.v, c, 0, 0, 0);
#else
  union { unsigned u[2]; s16x4 v; } A, B;
  A.u[0] = a0; A.u[1] = a1; B.u[0] = b0; B.u[1] = b1;
  return __builtin_amdgcn_mfma_f32_16x16x16bf16_1k(A.v, B.v, c, 0, 0, 0);
#endif
#else
  (void)a0; (void)a1; (void)b0; (void)b1;
  return c;  // host stub, never executed
#endif
}

// ---------------- converters ----------------

__global__ __launch_bounds__(256) void transpose_w4(
    const float* __restrict__ s0, const float* __restrict__ s1,
    const float* __restrict__ s2, const float* __restrict__ s3,
    ushort_t* __restrict__ d_qkv, ushort_t* __restrict__ d_o) {
  __shared__ float t[32][33];
  const int m = blockIdx.z;
  const float* src = (m == 0) ? s0 : (m == 1) ? s1 : (m == 2) ? s2 : s3;
  ushort_t* dst = (m < 3) ? (d_qkv + (size_t)m * DMODEL * DMODEL) : d_o;
  const int bi = blockIdx.x, bj = blockIdx.y;
  const int r = threadIdx.x >> 5, c = threadIdx.x & 31;
  for (int p = 0; p < 4; ++p)
    t[r + p * 8][c] = src[(size_t)(bi * 32 + r + p * 8) * DMODEL + bj * 32 + c];
  __syncthreads();
  for (int p = 0; p < 4; ++p)
    dst[(size_t)(bj * 32 + r + p * 8) * DMODEL + bi * 32 + c] = f2bf(t[c][r + p * 8]);
}

__global__ void convert_x(const float* __restrict__ in, ushort_t* __restrict__ out) {
  int idx = blockIdx.x * 256 + threadIdx.x;
  f32x4 v = ((const f32x4*)in)[idx];
  u16x4 o;
  o.x = f2bf(v.x); o.y = f2bf(v.y); o.z = f2bf(v.z); o.w = f2bf(v.w);
  ((u16x4*)out)[idx] = o;
}

// ---------------- GEMM: C[M x N] = A[M x K] * B^T (B stored [N][K]) ----------------
// mode 0: QKV epilogue (Q scaled (1/8)*log2e; V -> transposed [bh][d][n] via shfl-pair).
// mode 2: out-proj with FUSED split-combine A-staging (A = (o0+o1)/(l0+l1)), bias, fp32 out.
__global__ __launch_bounds__(256) void gemm_bt(
    const ushort_t* __restrict__ A, const ushort_t* __restrict__ B, int K, int mode,
    ushort_t* __restrict__ q_ws, ushort_t* __restrict__ k_ws, ushort_t* __restrict__ v_ws,
    float* __restrict__ outF, const float* __restrict__ bias,
    const ushort_t* __restrict__ opart, const float* __restrict__ lpart) {
  __shared__ __align__(16) ushort_t a_lds[128 * 32];
  __shared__ __align__(16) ushort_t b_lds[128 * 32];
  const int tid = threadIdx.x;
  const int w = tid >> 6, lane = tid & 63;
  const int quad = lane >> 4, l16 = lane & 15;
  const int wm = w >> 1, wn = w & 1;
  const size_t row0 = (size_t)blockIdx.x * 128;
  const size_t col0 = (size_t)blockIdx.y * 128;

  const int srow = w * 32 + (lane >> 2);
  const int kbyte = (lane & 3) * 16;
  const char* aG = (const char*)(A + (row0 + srow) * (size_t)K) + kbyte;
  const char* bG = (const char*)(B + (col0 + srow) * (size_t)K) + kbyte;
  const size_t rstep = (size_t)16 * K * 2;
  char* aL = (char*)a_lds + (size_t)(w * 2) * 1024;
  char* bL = (char*)b_lds + (size_t)(w * 2) * 1024;

  floatx4 acc[4][4];
  for (int i = 0; i < 4; ++i)
    for (int j = 0; j < 4; ++j) acc[i][j] = (floatx4){0.f, 0.f, 0.f, 0.f};

  const int nk = K / 32;
  for (int kt = 0; kt < nk; ++kt) {
    const size_t koff = (size_t)kt * 64;
    __syncthreads();
    if (mode == 2) {
      const int col = kt * 32 + (lane & 3) * 8;
      const int h = col >> 6, dd = col & 63;
#pragma unroll
      for (int sl = 0; sl < 2; ++sl) {
        int row = (int)row0 + srow + sl * 16;
        int b = row >> 12, n = row & 4095;
        int bh = b * NHEAD + h;
        size_t i0 = ((size_t)bh * NTOK + n) * HD + dd;
        size_t i1 = i0 + (size_t)NBH * NTOK * HD;
        u16x8 a = *(const u16x8*)&opart[i0];
        u16x8 c = *(const u16x8*)&opart[i1];
        float inv = 1.0f / (lpart[(size_t)bh * NTOK + n] + lpart[(size_t)(NBH + bh) * NTOK + n]);
        u16x8 o;
#pragma unroll
        for (int j = 0; j < 8; ++j) o[j] = f2bf((bf2f(a[j]) + bf2f(c[j])) * inv);
        *(u16x8*)(aL + sl * 1024 + (size_t)lane * 16) = o;
      }
    } else {
      async16(aG + koff, aL);
      async16(aG + koff + rstep, aL + 1024);
    }
    async16(bG + koff, bL);
    async16(bG + koff + rstep, bL + 1024);
    __syncthreads();
    bf16x8 af[4], bfr[4];
    for (int mt = 0; mt < 4; ++mt)
      af[mt] = *(bf16x8*)&a_lds[(wm * 64 + mt * 16 + l16) * 32 + quad * 8];
    for (int nt = 0; nt < 4; ++nt)
      bfr[nt] = *(bf16x8*)&b_lds[(wn * 64 + nt * 16 + l16) * 32 + quad * 8];
    for (int mt = 0; mt < 4; ++mt)
      for (int nt = 0; nt < 4; ++nt)
        acc[mt][nt] = __builtin_amdgcn_mfma_f32_16x16x32_bf16(af[mt], bfr[nt], acc[mt][nt], 0, 0, 0);
  }

  if (mode == 0) {
    const int which = (int)(col0 / DMODEL);
    if (which < 2) {
      ushort_t* dstT = (which == 0) ? q_ws : k_ws;
      const float scale = (which == 0) ? 0.125f * 1.4426950408889634f : 1.0f;
      for (int mt = 0; mt < 4; ++mt) {
        int gr = (int)row0 + wm * 64 + mt * 16 + quad * 4;
        int b = gr >> 12;
        int n0 = gr & 4095;
        for (int nt = 0; nt < 4; ++nt) {
          int gc = (int)col0 + wn * 64 + nt * 16 + l16;
          int cc = gc - which * DMODEL;
          int h = cc >> 6, d = cc & 63;
          size_t base = ((size_t)(b * NHEAD + h) * NTOK + n0) * HD + d;
          for (int r = 0; r < 4; ++r)
            dstT[base + (size_t)r * HD] = f2bf(acc[mt][nt][r] * scale);
        }
      }
    } else {  // V: transposed [bh][d][token]; pair quads via shfl -> 16B stores
      for (int mt = 0; mt < 4; ++mt) {
        int gr = (int)row0 + wm * 64 + mt * 16 + quad * 4;
        int b = gr >> 12;
        int n0 = gr & 4095;
        for (int nt = 0; nt < 4; ++nt) {
          int gc = (int)col0 + wn * 64 + nt * 16 + l16;
          int cc = gc - 2 * DMODEL;
          int h = cc >> 6, d = cc & 63;
          u16x4 ov;
          for (int r = 0; r < 4; ++r) ov[r] = f2bf(acc[mt][nt][r]);
          unsigned d0 = ((unsigned*)&ov)[0], d1 = ((unsigned*)&ov)[1];
          unsigned p0 = (unsigned)__shfl_xor((int)d0, 16);
          unsigned p1 = (unsigned)__shfl_xor((int)d1, 16);
          if (!(quad & 1)) {
            u16x8 pk;
            ((unsigned*)&pk)[0] = d0; ((unsigned*)&pk)[1] = d1;
            ((unsigned*)&pk)[2] = p0; ((unsigned*)&pk)[3] = p1;
            *(u16x8*)&v_ws[((size_t)(b * NHEAD + h) * HD + d) * NTOK + n0] = pk;
          }
        }
      }
    }
  } else {
    for (int mt = 0; mt < 4; ++mt) {
      int gr = (int)row0 + wm * 64 + mt * 16 + quad * 4;
      for (int nt = 0; nt < 4; ++nt) {
        int gc = (int)col0 + wn * 64 + nt * 16 + l16;
        float bv = bias[gc];
        for (int r = 0; r < 4; ++r)
          outF[(size_t)(gr + r) * DMODEL + gc] = acc[mt][nt][r] + bv;
      }
    }
  }
}

// ---------------- flash attention v7 ----------------
// 4 waves x 32 q-rows (BQ=128), split x2, pairing, XCD homing — attn5 shape — BUT:
//  * PV via mfma_16x16x16: exp'd S^T C-layout IS the A-frag-16 layout -> P stays in
//    registers (no ds_write / lgkmcnt / ds_read round trip).
//  * V staged into swizzled d-rows: unit p = (u + 4*(d&3)) & 15 -> B-frag-16 b64
//    reads land exactly 4 lanes per 8B unit = conflict-free at port rate.
//  * Q staged through the idle dbuf half -> LDS 32 KB -> 5 blocks/CU.
__global__ __launch_bounds__(256) void attn7(
    const ushort_t* __restrict__ Qh, const ushort_t* __restrict__ Kh,
    const ushort_t* __restrict__ Vt, ushort_t* __restrict__ o_part,
    float* __restrict__ l_part) {
  __shared__ __align__(16) ushort_t k_lds[2][8 * 512];   // A-frag linear K, dbuf (16 KB)
  __shared__ __align__(16) ushort_t v_lds[2][8 * 512];   // swizzled V^T d-rows, dbuf (16 KB)
  const int tid = threadIdx.x;
  const int w = tid >> 6, lane = tid & 63;
  const int quad = lane >> 4, l16 = lane & 15;
  const int bh = blockIdx.x;   // XCD = bh % 8
  const int split = blockIdx.z;
  const size_t hbase = (size_t)bh * NTOK * HD;
  const ushort_t* Qb = Qh + hbase;
  const ushort_t* Kb = Kh + hbase;
  const ushort_t* Vb = Vt + hbase;  // [64][4096]
  const size_t obase = ((size_t)split * NBH + bh) * NTOK * HD;
  const size_t lbase = ((size_t)split * NBH + bh) * NTOK;

  // V staging swizzle (per-thread invariants): lane covers d-row vrow of its slot;
  // source key offset rotated by 4*(vrow&3) 8B-units (4 keys each).
  const int vrow = lane >> 3;
  const int vc = lane & 7;
  const int vkoff = ((2 * vc + 16 - 4 * (vrow & 3)) & 15) * 4;
  // V read rotation: unit p(g) = (g*4 + quad + 4*(l16&3)) & 15
  const int psw = quad + 4 * (l16 & 3);

  for (int phase = 0; phase < 2; ++phase) {
    const int qt = (phase == 0) ? (int)blockIdx.y : 31 - (int)blockIdx.y;
    const int Q0 = qt * 128;
    const int nkt = 2 * qt + 2;
    const int kt_lo = (split == 0) ? 0 : nkt / 2;
    const int nit = nkt / 2;  // qt+1 per split, uniform over pairing
    __syncthreads();  // all waves done with dbuf from previous phase
    // stage Q through the idle dbuf half (buf1): waves 0,1 -> k_lds[1]; 2,3 -> v_lds[1]
    char* qstage = (w < 2) ? ((char*)k_lds + 8192 + w * 4096)
                           : ((char*)v_lds + 8192 + (w - 2) * 4096);
#pragma unroll
    for (int i = 0; i < 4; ++i)
      async16(Qb + (size_t)(Q0 + w * 32 + (i >> 1) * 16 + l16) * HD + (i & 1) * 32 + quad * 8,
              qstage + i * 1024);
    // prefetch first K/V tile into buf0 (per wave 2 K + 2 V slots)
    {
      const int k0p = kt_lo * 64;
#pragma unroll
      for (int i = 0; i < 2; ++i) {
        int s = w * 2 + i;
        async16(Kb + (size_t)(k0p + (s >> 1) * 16 + l16) * HD + (s & 1) * 32 + quad * 8,
                (char*)k_lds + s * 1024);
        async16(Vb + (size_t)(s * 8 + vrow) * NTOK + k0p + vkoff,
                (char*)v_lds + s * 1024);
      }
    }
    __asm volatile("s_waitcnt vmcnt(0)" ::: "memory");
    bf16x8 qr[2][2];  // own wave's Q slots -> no barrier needed before reading
#pragma unroll
    for (int qf = 0; qf < 2; ++qf)
#pragma unroll
      for (int hh = 0; hh < 2; ++hh)
        qr[qf][hh] = *(const bf16x8*)(qstage + (qf * 2 + hh) * 1024 + lane * 16);

    floatx4 o[2][4];
    float lp[2] = {0.f, 0.f};
#pragma unroll
    for (int qf = 0; qf < 2; ++qf)
#pragma unroll
      for (int dt = 0; dt < 4; ++dt) o[qf][dt] = (floatx4){0.f, 0.f, 0.f, 0.f};

    const int wq0 = Q0 + w * 32;

    for (int it = 0; it < nit; ++it) {
      const int kt = kt_lo + it;
      const int cur = it & 1;
      __syncthreads();  // buf[cur] staged + buf[cur^1] free (incl. Q stage at it=0)
      if (it + 1 < nit) {
        const int k1 = (kt + 1) * 64;
#pragma unroll
        for (int i = 0; i < 2; ++i) {
          int s = w * 2 + i;
          async16(Kb + (size_t)(k1 + (s >> 1) * 16 + l16) * HD + (s & 1) * 32 + quad * 8,
                  (char*)k_lds + (cur ^ 1) * 8192 + s * 1024);
          async16(Vb + (size_t)(s * 8 + vrow) * NTOK + k1 + vkoff,
                  (char*)v_lds + (cur ^ 1) * 8192 + s * 1024);
        }
      }
      const int k0 = kt * 64;
      if (k0 > wq0 + 31) continue;  // tile fully above this wave's diagonal
      const char* kb = (const char*)k_lds + cur * 8192;
      const char* vb = (const char*)v_lds + cur * 8192;
      const bool need_mask = (k0 + 63 > wq0);

      // per 16-key chunk g: QK (K=32 MFMA x4) -> exp/pack -> PV (K=16 MFMA x8)
#pragma unroll
      for (int g = 0; g < 4; ++g) {
        bf16x8 kf0 = *(const bf16x8*)(kb + (g * 2 + 0) * 1024 + lane * 16);
        bf16x8 kf1 = *(const bf16x8*)(kb + (g * 2 + 1) * 1024 + lane * 16);
        floatx4 z0 = (floatx4){0.f, 0.f, 0.f, 0.f};
        floatx4 z1 = (floatx4){0.f, 0.f, 0.f, 0.f};
        z0 = __builtin_amdgcn_mfma_f32_16x16x32_bf16(kf0, qr[0][0], z0, 0, 0, 0);
        z1 = __builtin_amdgcn_mfma_f32_16x16x32_bf16(kf0, qr[1][0], z1, 0, 0, 0);
        z0 = __builtin_amdgcn_mfma_f32_16x16x32_bf16(kf1, qr[0][1], z0, 0, 0, 0);
        z1 = __builtin_amdgcn_mfma_f32_16x16x32_bf16(kf1, qr[1][1], z1, 0, 0, 0);
        unsigned pa[2][2];
#pragma unroll
        for (int qf = 0; qf < 2; ++qf) {
          floatx4 z = qf ? z1 : z0;
          float p[4];
          const int qg = wq0 + qf * 16 + l16;
#pragma unroll
          for (int r = 0; r < 4; ++r) {
            float e = __builtin_exp2f(z[r]);  // Q pre-scaled by log2e/8
            if (need_mask && (k0 + g * 16 + quad * 4 + r > qg)) e = 0.f;
            p[r] = e;
          }
          lp[qf] += (p[0] + p[1]) + (p[2] + p[3]);
          union { float f; unsigned u; } c0, c1, c2, c3;
          c0.f = p[0]; c1.f = p[1]; c2.f = p[2]; c3.f = p[3];
          pa[qf][0] = __builtin_amdgcn_perm(c1.u, c0.u, 0x07060302u);  // {bf16 p0, p1}
          pa[qf][1] = __builtin_amdgcn_perm(c3.u, c2.u, 0x07060302u);  // {bf16 p2, p3}
        }
        const int pofs = ((g * 4 + psw) & 15) * 8;
#pragma unroll
        for (int dt = 0; dt < 4; ++dt) {
          u32x2 vv = *(const u32x2*)(vb + dt * 2048 + l16 * 128 + pofs);
          o[0][dt] = mfma16(pa[0][0], pa[0][1], vv.x, vv.y, o[0][dt]);
          o[1][dt] = mfma16(pa[1][0], pa[1][1], vv.x, vv.y, o[1][dt]);
        }
      }
    }

    // epilogue: unnormalized partial o (bf16) + per-row l (fp32)
#pragma unroll
    for (int qf = 0; qf < 2; ++qf) {
      float lf = lp[qf];
      lf += __shfl_xor(lf, 16);
      lf += __shfl_xor(lf, 32);
#pragma unroll
      for (int r = 0; r < 4; ++r) {
        float lq = __shfl(lf, quad * 4 + r);
        int qg = wq0 + qf * 16 + quad * 4 + r;
        size_t base = obase + (size_t)qg * HD;
#pragma unroll
        for (int dt = 0; dt < 4; ++dt)
          o_part[base + dt * 16 + l16] = f2bf(o[qf][dt][r]);
        if (l16 == 0) l_part[lbase + qg] = lq;
      }
    }
  }
}

// ---------------- launch ----------------
extern "C" void kernel_launch(void* const* d_in, const int* in_sizes, int n_in,
                              void* d_out, int out_size, void* d_ws, size_t ws_size,
                              hipStream_t stream) {
  const float* x  = (const float*)d_in[0];
  const float* wq = (const float*)d_in[1];
  const float* wk = (const float*)d_in[2];
  const float* wv = (const float*)d_in[3];
  const float* wo = (const float*)d_in[4];
  const float* bo = (const float*)d_in[5];
  float* out = (float*)d_out;

  ushort_t* ws = (ushort_t*)d_ws;
  ushort_t* wqkvT = ws;                               // 2304*768
  ushort_t* woutT = wqkvT + 2304 * 768;               // 768*768
  ushort_t* xbf   = woutT + 768 * 768;                // 8192*768 (x bf16)
  ushort_t* qh    = xbf + (size_t)NROWS * DMODEL;     // 24*4096*64
  ushort_t* kh    = qh + (size_t)NBH * NTOK * HD;
  ushort_t* vt    = kh + (size_t)NBH * NTOK * HD;     // V transposed [bh][64][4096]
  ushort_t* opart = vt + (size_t)NBH * NTOK * HD;     // 2*24*4096*64 bf16
  float*    lpart = (float*)(opart + (size_t)2 * NBH * NTOK * HD);  // 2*24*4096 fp32

  transpose_w4<<<dim3(24, 24, 4), 256, 0, stream>>>(wq, wk, wv, wo, wqkvT, woutT);
  convert_x<<<6144, 256, 0, stream>>>(x, xbf);

  gemm_bt<<<dim3(64, 18), 256, 0, stream>>>(xbf, wqkvT, DMODEL, 0,
                                            qh, kh, vt, nullptr, nullptr, nullptr, nullptr);
  attn7<<<dim3(24, 16, 2), 256, 0, stream>>>(qh, kh, vt, opart, lpart);
  gemm_bt<<<dim3(64, 6), 256, 0, stream>>>(opart, woutT, DMODEL, 2,
                                           nullptr, nullptr, nullptr, out, bo, opart, lpart);
}

// Round 9
// 269.938 us; speedup vs baseline: 1.1595x; 1.0477x over previous
//
#include <hip/hip_runtime.h>

typedef unsigned short ushort_t;
typedef __bf16 bf16_t;
typedef float floatx4 __attribute__((ext_vector_type(4)));
typedef bf16_t bf16x8 __attribute__((ext_vector_type(8)));
typedef bf16_t bf16x4 __attribute__((ext_vector_type(4)));
typedef short s16x4 __attribute__((ext_vector_type(4)));
typedef float f32x4 __attribute__((ext_vector_type(4)));
typedef unsigned short u16x4 __attribute__((ext_vector_type(4)));
typedef unsigned short u16x8 __attribute__((ext_vector_type(8)));
typedef unsigned int u32x2 __attribute__((ext_vector_type(2)));

#define NTOK 4096
#define NHEAD 12
#define HD 64
#define DMODEL 768
#define NROWS 8192  // 2*4096
#define NBH 24

__device__ __forceinline__ ushort_t f2bf(float f) {
  union { float f; unsigned u; } v; v.f = f;
  unsigned u = v.u;
  unsigned r = u + 0x7fffu + ((u >> 16) & 1u);
  return (ushort_t)(r >> 16);
}

__device__ __forceinline__ float bf2f(ushort_t s) {
  union { unsigned u; float f; } v; v.u = (unsigned)s << 16; return v.f;
}

__device__ __forceinline__ void async16(const void* g, void* l) {
  __builtin_amdgcn_global_load_lds(
      (const __attribute__((address_space(1))) void*)g,
      (__attribute__((address_space(3))) void*)l, 16, 0, 0);
}

// K=16 bf16 MFMA: A/B = 4 bf16 (2 VGPRs). Guarded for the host pass.
__device__ __forceinline__ floatx4 mfma16(unsigned a0, unsigned a1,
                                          unsigned b0, unsigned b1, floatx4 c) {
#if defined(__HIP_DEVICE_COMPILE__)
#if __has_builtin(__builtin_amdgcn_mfma_f32_16x16x16_bf16)
  union { unsigned u[2]; bf16x4 v; } A, B;
  A.u[0] = a0; A.u[1] = a1; B.u[0] = b0; B.u[1] = b1;
  return __builtin_amdgcn_mfma_f32_16x16x16_bf16(A.v, B.v, c, 0, 0, 0);
#else
  union { unsigned u[2]; s16x4 v; } A, B;
  A.u[0] = a0; A.u[1] = a1; B.u[0] = b0; B.u[1] = b1;
  return __builtin_amdgcn_mfma_f32_16x16x16bf16_1k(A.v, B.v, c, 0, 0, 0);
#endif
#else
  (void)a0; (void)a1; (void)b0; (void)b1;
  return c;  // host stub, never executed
#endif
}

// ---------------- converters ----------------

__global__ __launch_bounds__(256) void transpose_w4(
    const float* __restrict__ s0, const float* __restrict__ s1,
    const float* __restrict__ s2, const float* __restrict__ s3,
    ushort_t* __restrict__ d_qkv, ushort_t* __restrict__ d_o) {
  __shared__ float t[32][33];
  const int m = blockIdx.z;
  const float* src = (m == 0) ? s0 : (m == 1) ? s1 : (m == 2) ? s2 : s3;
  ushort_t* dst = (m < 3) ? (d_qkv + (size_t)m * DMODEL * DMODEL) : d_o;
  const int bi = blockIdx.x, bj = blockIdx.y;
  const int r = threadIdx.x >> 5, c = threadIdx.x & 31;
  for (int p = 0; p < 4; ++p)
    t[r + p * 8][c] = src[(size_t)(bi * 32 + r + p * 8) * DMODEL + bj * 32 + c];
  __syncthreads();
  for (int p = 0; p < 4; ++p)
    dst[(size_t)(bj * 32 + r + p * 8) * DMODEL + bi * 32 + c] = f2bf(t[c][r + p * 8]);
}

__global__ void convert_x(const float* __restrict__ in, ushort_t* __restrict__ out) {
  int idx = blockIdx.x * 256 + threadIdx.x;
  f32x4 v = ((const f32x4*)in)[idx];
  u16x4 o;
  o.x = f2bf(v.x); o.y = f2bf(v.y); o.z = f2bf(v.z); o.w = f2bf(v.w);
  ((u16x4*)out)[idx] = o;
}

// ---------------- GEMM: C[M x N] = A[M x K] * B^T (B stored [N][K]) ----------------
// mode 0: QKV epilogue (Q scaled (1/8)*log2e; V -> transposed [bh][d][n] via shfl-pair).
// mode 2: out-proj with FUSED split-combine A-staging (A = (o0+o1)/(l0+l1)), bias, fp32 out.
__global__ __launch_bounds__(256) void gemm_bt(
    const ushort_t* __restrict__ A, const ushort_t* __restrict__ B, int K, int mode,
    ushort_t* __restrict__ q_ws, ushort_t* __restrict__ k_ws, ushort_t* __restrict__ v_ws,
    float* __restrict__ outF, const float* __restrict__ bias,
    const ushort_t* __restrict__ opart, const float* __restrict__ lpart) {
  __shared__ __align__(16) ushort_t a_lds[128 * 32];
  __shared__ __align__(16) ushort_t b_lds[128 * 32];
  const int tid = threadIdx.x;
  const int w = tid >> 6, lane = tid & 63;
  const int quad = lane >> 4, l16 = lane & 15;
  const int wm = w >> 1, wn = w & 1;
  const size_t row0 = (size_t)blockIdx.x * 128;
  const size_t col0 = (size_t)blockIdx.y * 128;

  const int srow = w * 32 + (lane >> 2);
  const int kbyte = (lane & 3) * 16;
  const char* aG = (const char*)(A + (row0 + srow) * (size_t)K) + kbyte;
  const char* bG = (const char*)(B + (col0 + srow) * (size_t)K) + kbyte;
  const size_t rstep = (size_t)16 * K * 2;
  char* aL = (char*)a_lds + (size_t)(w * 2) * 1024;
  char* bL = (char*)b_lds + (size_t)(w * 2) * 1024;

  floatx4 acc[4][4];
  for (int i = 0; i < 4; ++i)
    for (int j = 0; j < 4; ++j) acc[i][j] = (floatx4){0.f, 0.f, 0.f, 0.f};

  const int nk = K / 32;
  for (int kt = 0; kt < nk; ++kt) {
    const size_t koff = (size_t)kt * 64;
    __syncthreads();
    if (mode == 2) {
      const int col = kt * 32 + (lane & 3) * 8;
      const int h = col >> 6, dd = col & 63;
#pragma unroll
      for (int sl = 0; sl < 2; ++sl) {
        int row = (int)row0 + srow + sl * 16;
        int b = row >> 12, n = row & 4095;
        int bh = b * NHEAD + h;
        size_t i0 = ((size_t)bh * NTOK + n) * HD + dd;
        size_t i1 = i0 + (size_t)NBH * NTOK * HD;
        u16x8 a = *(const u16x8*)&opart[i0];
        u16x8 c = *(const u16x8*)&opart[i1];
        float inv = 1.0f / (lpart[(size_t)bh * NTOK + n] + lpart[(size_t)(NBH + bh) * NTOK + n]);
        u16x8 o;
#pragma unroll
        for (int j = 0; j < 8; ++j) o[j] = f2bf((bf2f(a[j]) + bf2f(c[j])) * inv);
        *(u16x8*)(aL + sl * 1024 + (size_t)lane * 16) = o;
      }
    } else {
      async16(aG + koff, aL);
      async16(aG + koff + rstep, aL + 1024);
    }
    async16(bG + koff, bL);
    async16(bG + koff + rstep, bL + 1024);
    __syncthreads();
    bf16x8 af[4], bfr[4];
    for (int mt = 0; mt < 4; ++mt)
      af[mt] = *(bf16x8*)&a_lds[(wm * 64 + mt * 16 + l16) * 32 + quad * 8];
    for (int nt = 0; nt < 4; ++nt)
      bfr[nt] = *(bf16x8*)&b_lds[(wn * 64 + nt * 16 + l16) * 32 + quad * 8];
    for (int mt = 0; mt < 4; ++mt)
      for (int nt = 0; nt < 4; ++nt)
        acc[mt][nt] = __builtin_amdgcn_mfma_f32_16x16x32_bf16(af[mt], bfr[nt], acc[mt][nt], 0, 0, 0);
  }

  if (mode == 0) {
    const int which = (int)(col0 / DMODEL);
    if (which < 2) {
      ushort_t* dstT = (which == 0) ? q_ws : k_ws;
      const float scale = (which == 0) ? 0.125f * 1.4426950408889634f : 1.0f;
      for (int mt = 0; mt < 4; ++mt) {
        int gr = (int)row0 + wm * 64 + mt * 16 + quad * 4;
        int b = gr >> 12;
        int n0 = gr & 4095;
        for (int nt = 0; nt < 4; ++nt) {
          int gc = (int)col0 + wn * 64 + nt * 16 + l16;
          int cc = gc - which * DMODEL;
          int h = cc >> 6, d = cc & 63;
          size_t base = ((size_t)(b * NHEAD + h) * NTOK + n0) * HD + d;
          for (int r = 0; r < 4; ++r)
            dstT[base + (size_t)r * HD] = f2bf(acc[mt][nt][r] * scale);
        }
      }
    } else {  // V: transposed [bh][d][token]; pair quads via shfl -> 16B stores
      for (int mt = 0; mt < 4; ++mt) {
        int gr = (int)row0 + wm * 64 + mt * 16 + quad * 4;
        int b = gr >> 12;
        int n0 = gr & 4095;
        for (int nt = 0; nt < 4; ++nt) {
          int gc = (int)col0 + wn * 64 + nt * 16 + l16;
          int cc = gc - 2 * DMODEL;
          int h = cc >> 6, d = cc & 63;
          u16x4 ov;
          for (int r = 0; r < 4; ++r) ov[r] = f2bf(acc[mt][nt][r]);
          unsigned d0 = ((unsigned*)&ov)[0], d1 = ((unsigned*)&ov)[1];
          unsigned p0 = (unsigned)__shfl_xor((int)d0, 16);
          unsigned p1 = (unsigned)__shfl_xor((int)d1, 16);
          if (!(quad & 1)) {
            u16x8 pk;
            ((unsigned*)&pk)[0] = d0; ((unsigned*)&pk)[1] = d1;
            ((unsigned*)&pk)[2] = p0; ((unsigned*)&pk)[3] = p1;
            *(u16x8*)&v_ws[((size_t)(b * NHEAD + h) * HD + d) * NTOK + n0] = pk;
          }
        }
      }
    }
  } else {
    for (int mt = 0; mt < 4; ++mt) {
      int gr = (int)row0 + wm * 64 + mt * 16 + quad * 4;
      for (int nt = 0; nt < 4; ++nt) {
        int gc = (int)col0 + wn * 64 + nt * 16 + l16;
        float bv = bias[gc];
        for (int r = 0; r < 4; ++r)
          outF[(size_t)(gr + r) * DMODEL + gc] = acc[mt][nt][r] + bv;
      }
    }
  }
}

// ---------------- flash attention v8 ----------------
// attn7 structure (P register-resident via mfma16, Q in idle dbuf, split x2,
// pairing, XCD homing) with two fixes:
//  * V swizzle redone at 16B-chunk granularity, rotation = d&7:
//    row d holds chunk U at position P=(U+(d&7))&7. Read banks: exactly 2
//    lanes/bank per phase (free, m136). R8's 8B/4*(l16&3) rotation aliased
//    with quad -> 4-way conflicts (19.2M counter).
//  * ALL LDS reads (8x K b128 + 16x V b64) hoisted to iter start — V reads
//    don't depend on exp — so the per-g chain is MFMA->exp->MFMA with no
//    embedded ~120cy ds_read latency; g+1 QK overlaps g PV.
__global__ __launch_bounds__(256, 3) void attn8(
    const ushort_t* __restrict__ Qh, const ushort_t* __restrict__ Kh,
    const ushort_t* __restrict__ Vt, ushort_t* __restrict__ o_part,
    float* __restrict__ l_part) {
  __shared__ __align__(16) ushort_t k_lds[2][8 * 512];   // A-frag linear K, dbuf (16 KB)
  __shared__ __align__(16) ushort_t v_lds[2][8 * 512];   // chunk-swizzled V^T rows, dbuf (16 KB)
  const int tid = threadIdx.x;
  const int w = tid >> 6, lane = tid & 63;
  const int quad = lane >> 4, l16 = lane & 15;
  const int bh = blockIdx.x;   // XCD = bh % 8
  const int split = blockIdx.z;
  const size_t hbase = (size_t)bh * NTOK * HD;
  const ushort_t* Qb = Qh + hbase;
  const ushort_t* Kb = Kh + hbase;
  const ushort_t* Vb = Vt + hbase;  // [64][4096]
  const size_t obase = ((size_t)split * NBH + bh) * NTOK * HD;
  const size_t lbase = ((size_t)split * NBH + bh) * NTOK;

  // V staging (async16 dest = base + lane*16): lane covers d-row vrow = lane>>3,
  // chunk position vc = lane&7; source chunk = (vc - vrow) & 7 (8 keys each).
  const int vrow = lane >> 3;
  const int vc = lane & 7;
  const int vkoff = ((vc - vrow) & 7) * 8;  // in ushort elements
  // V read: row byte base + half-select; P(g) = (g*2 + padd) & 7.
  const int vrbase = l16 * 128 + (quad & 1) * 8;
  const int padd = (quad >> 1) + (l16 & 7);

  for (int phase = 0; phase < 2; ++phase) {
    const int qt = (phase == 0) ? (int)blockIdx.y : 31 - (int)blockIdx.y;
    const int Q0 = qt * 128;
    const int nkt = 2 * qt + 2;
    const int kt_lo = (split == 0) ? 0 : nkt / 2;
    const int nit = nkt / 2;  // qt+1 per split, uniform over pairing
    __syncthreads();  // all waves done with dbuf from previous phase
    // stage Q through the idle dbuf half (buf1): waves 0,1 -> k_lds[1]; 2,3 -> v_lds[1]
    char* qstage = (w < 2) ? ((char*)k_lds + 8192 + w * 4096)
                           : ((char*)v_lds + 8192 + (w - 2) * 4096);
#pragma unroll
    for (int i = 0; i < 4; ++i)
      async16(Qb + (size_t)(Q0 + w * 32 + (i >> 1) * 16 + l16) * HD + (i & 1) * 32 + quad * 8,
              qstage + i * 1024);
    // prefetch first K/V tile into buf0 (per wave 2 K + 2 V slots)
    {
      const int k0p = kt_lo * 64;
#pragma unroll
      for (int i = 0; i < 2; ++i) {
        int s = w * 2 + i;
        async16(Kb + (size_t)(k0p + (s >> 1) * 16 + l16) * HD + (s & 1) * 32 + quad * 8,
                (char*)k_lds + s * 1024);
        async16(Vb + (size_t)(s * 8 + vrow) * NTOK + k0p + vkoff,
                (char*)v_lds + s * 1024);
      }
    }
    __asm volatile("s_waitcnt vmcnt(0)" ::: "memory");
    bf16x8 qr[2][2];  // own wave's Q slots -> no barrier needed before reading
#pragma unroll
    for (int qf = 0; qf < 2; ++qf)
#pragma unroll
      for (int hh = 0; hh < 2; ++hh)
        qr[qf][hh] = *(const bf16x8*)(qstage + (qf * 2 + hh) * 1024 + lane * 16);

    floatx4 o[2][4];
    float lp[2] = {0.f, 0.f};
#pragma unroll
    for (int qf = 0; qf < 2; ++qf)
#pragma unroll
      for (int dt = 0; dt < 4; ++dt) o[qf][dt] = (floatx4){0.f, 0.f, 0.f, 0.f};

    const int wq0 = Q0 + w * 32;

    for (int it = 0; it < nit; ++it) {
      const int kt = kt_lo + it;
      const int cur = it & 1;
      __syncthreads();  // buf[cur] staged + buf[cur^1] free (incl. Q stage at it=0)
      if (it + 1 < nit) {
        const int k1 = (kt + 1) * 64;
#pragma unroll
        for (int i = 0; i < 2; ++i) {
          int s = w * 2 + i;
          async16(Kb + (size_t)(k1 + (s >> 1) * 16 + l16) * HD + (s & 1) * 32 + quad * 8,
                  (char*)k_lds + (cur ^ 1) * 8192 + s * 1024);
          async16(Vb + (size_t)(s * 8 + vrow) * NTOK + k1 + vkoff,
                  (char*)v_lds + (cur ^ 1) * 8192 + s * 1024);
        }
      }
      const int k0 = kt * 64;
      if (k0 > wq0 + 31) continue;  // tile fully above this wave's diagonal
      const char* kb = (const char*)k_lds + cur * 8192;
      const char* vb = (const char*)v_lds + cur * 8192;
      const bool need_mask = (k0 + 63 > wq0);

      // hoist ALL tile LDS reads (independent of compute)
      bf16x8 kf[8];
#pragma unroll
      for (int j = 0; j < 8; ++j)
        kf[j] = *(const bf16x8*)(kb + j * 1024 + lane * 16);
      u32x2 vv[4][4];
#pragma unroll
      for (int g = 0; g < 4; ++g) {
        const int pofs = ((g * 2 + padd) & 7) * 16;
#pragma unroll
        for (int dt = 0; dt < 4; ++dt)
          vv[g][dt] = *(const u32x2*)(vb + dt * 2048 + vrbase + pofs);
      }

      // per 16-key chunk g: QK (K=32 x4) -> exp/pack -> PV (K=16 x8, reg A)
#pragma unroll
      for (int g = 0; g < 4; ++g) {
        floatx4 z0 = (floatx4){0.f, 0.f, 0.f, 0.f};
        floatx4 z1 = (floatx4){0.f, 0.f, 0.f, 0.f};
        z0 = __builtin_amdgcn_mfma_f32_16x16x32_bf16(kf[g * 2 + 0], qr[0][0], z0, 0, 0, 0);
        z1 = __builtin_amdgcn_mfma_f32_16x16x32_bf16(kf[g * 2 + 0], qr[1][0], z1, 0, 0, 0);
        z0 = __builtin_amdgcn_mfma_f32_16x16x32_bf16(kf[g * 2 + 1], qr[0][1], z0, 0, 0, 0);
        z1 = __builtin_amdgcn_mfma_f32_16x16x32_bf16(kf[g * 2 + 1], qr[1][1], z1, 0, 0, 0);
        unsigned pa[2][2];
#pragma unroll
        for (int qf = 0; qf < 2; ++qf) {
          floatx4 z = qf ? z1 : z0;
          float p[4];
          const int qg = wq0 + qf * 16 + l16;
#pragma unroll
          for (int r = 0; r < 4; ++r) {
            float e = __builtin_exp2f(z[r]);  // Q pre-scaled by log2e/8
            if (need_mask && (k0 + g * 16 + quad * 4 + r > qg)) e = 0.f;
            p[r] = e;
          }
          lp[qf] += (p[0] + p[1]) + (p[2] + p[3]);
          union { float f; unsigned u; } c0, c1, c2, c3;
          c0.f = p[0]; c1.f = p[1]; c2.f = p[2]; c3.f = p[3];
          pa[qf][0] = __builtin_amdgcn_perm(c1.u, c0.u, 0x07060302u);  // {bf16 p0, p1}
          pa[qf][1] = __builtin_amdgcn_perm(c3.u, c2.u, 0x07060302u);  // {bf16 p2, p3}
        }
#pragma unroll
        for (int dt = 0; dt < 4; ++dt) {
          o[0][dt] = mfma16(pa[0][0], pa[0][1], vv[g][dt].x, vv[g][dt].y, o[0][dt]);
          o[1][dt] = mfma16(pa[1][0], pa[1][1], vv[g][dt].x, vv[g][dt].y, o[1][dt]);
        }
      }
    }

    // epilogue: unnormalized partial o (bf16) + per-row l (fp32)
#pragma unroll
    for (int qf = 0; qf < 2; ++qf) {
      float lf = lp[qf];
      lf += __shfl_xor(lf, 16);
      lf += __shfl_xor(lf, 32);
#pragma unroll
      for (int r = 0; r < 4; ++r) {
        float lq = __shfl(lf, quad * 4 + r);
        int qg = wq0 + qf * 16 + quad * 4 + r;
        size_t base = obase + (size_t)qg * HD;
#pragma unroll
        for (int dt = 0; dt < 4; ++dt)
          o_part[base + dt * 16 + l16] = f2bf(o[qf][dt][r]);
        if (l16 == 0) l_part[lbase + qg] = lq;
      }
    }
  }
}

// ---------------- launch ----------------
extern "C" void kernel_launch(void* const* d_in, const int* in_sizes, int n_in,
                              void* d_out, int out_size, void* d_ws, size_t ws_size,
                              hipStream_t stream) {
  const float* x  = (const float*)d_in[0];
  const float* wq = (const float*)d_in[1];
  const float* wk = (const float*)d_in[2];
  const float* wv = (const float*)d_in[3];
  const float* wo = (const float*)d_in[4];
  const float* bo = (const float*)d_in[5];
  float* out = (float*)d_out;

  ushort_t* ws = (ushort_t*)d_ws;
  ushort_t* wqkvT = ws;                               // 2304*768
  ushort_t* woutT = wqkvT + 2304 * 768;               // 768*768
  ushort_t* xbf   = woutT + 768 * 768;                // 8192*768 (x bf16)
  ushort_t* qh    = xbf + (size_t)NROWS * DMODEL;     // 24*4096*64
  ushort_t* kh    = qh + (size_t)NBH * NTOK * HD;
  ushort_t* vt    = kh + (size_t)NBH * NTOK * HD;     // V transposed [bh][64][4096]
  ushort_t* opart = vt + (size_t)NBH * NTOK * HD;     // 2*24*4096*64 bf16
  float*    lpart = (float*)(opart + (size_t)2 * NBH * NTOK * HD);  // 2*24*4096 fp32

  transpose_w4<<<dim3(24, 24, 4), 256, 0, stream>>>(wq, wk, wv, wo, wqkvT, woutT);
  convert_x<<<6144, 256, 0, stream>>>(x, xbf);

  gemm_bt<<<dim3(64, 18), 256, 0, stream>>>(xbf, wqkvT, DMODEL, 0,
                                            qh, kh, vt, nullptr, nullptr, nullptr, nullptr);
  attn8<<<dim3(24, 16, 2), 256, 0, stream>>>(qh, kh, vt, opart, lpart);
  gemm_bt<<<dim3(64, 6), 256, 0, stream>>>(opart, woutT, DMODEL, 2,
                                           nullptr, nullptr, nullptr, out, bo, opart, lpart);
}